// Round 1
// baseline (7863.385 us; speedup 1.0000x reference)
//
#include <hip/hip_runtime.h>
#include <cstdint>

#define SEQ   1024
#define BATCH 128
#define INP   128
#define HID   512
#define OUTP  64
#define M1    (SEQ*BATCH)          // 131072

#define OMA_F   0.8f               // 1 - alpha
#define AL_F    0.2f               // alpha
#define SIGMA_F 0.031622776601683794f  // sqrt(2*0.2)*0.05

#define NGROUP  32                 // batch groups (4 rows each)
#define NSLICE  8                  // j-slices per group (64 j each)

// ---------------------------------------------------------------------------
// Phase 1: proj[s,b,h] = sum_i x[s,b,i]*W_in[h,i] + b_in[h]
// Written into the rnn_activity region of d_out (scan overwrites in place).
// Tiled 64x64, K=128 in two 64-chunks. 256 threads, 4x4 microtile.
// ---------------------------------------------------------------------------
__global__ __launch_bounds__(256) void proj_gemm_kernel(
    const float* __restrict__ x, const float* __restrict__ W_in,
    const float* __restrict__ b_in, float* __restrict__ act)
{
    __shared__ __align__(16) float xs[64*68];
    __shared__ __align__(16) float ws[64*70];
    const int bid = blockIdx.x;
    const int mt = bid >> 3, nt = bid & 7;
    const int m0 = mt << 6, n0 = nt << 6;
    const int t  = threadIdx.x;
    const int tm = t >> 4, tn = t & 15;
    float acc[4][4] = {{0.f,0.f,0.f,0.f},{0.f,0.f,0.f,0.f},
                       {0.f,0.f,0.f,0.f},{0.f,0.f,0.f,0.f}};
    for (int kc = 0; kc < INP; kc += 64) {
        #pragma unroll
        for (int n = 0; n < 4; n++) {
            int f = n*256 + t;
            int row = f >> 4, c4 = (f & 15) << 2;
            float4 v = *(const float4*)&x[(size_t)(m0+row)*INP + kc + c4];
            *(float4*)&xs[row*68 + c4] = v;
        }
        #pragma unroll
        for (int n = 0; n < 4; n++) {
            int f = n*256 + t;
            int row = f >> 4, c4 = (f & 15) << 2;
            float4 v = *(const float4*)&W_in[(size_t)(n0+row)*INP + kc + c4];
            *(float2*)&ws[row*70 + c4]     = make_float2(v.x, v.y);
            *(float2*)&ws[row*70 + c4 + 2] = make_float2(v.z, v.w);
        }
        __syncthreads();
        #pragma unroll
        for (int k = 0; k < 64; k += 4) {
            float4 xv[4]; float4 wv[4];
            #pragma unroll
            for (int i = 0; i < 4; i++)
                xv[i] = *(const float4*)&xs[(tm*4+i)*68 + k];
            #pragma unroll
            for (int jj = 0; jj < 4; jj++) {
                float2 a = *(const float2*)&ws[(tn*4+jj)*70 + k];
                float2 b = *(const float2*)&ws[(tn*4+jj)*70 + k + 2];
                wv[jj] = make_float4(a.x, a.y, b.x, b.y);
            }
            #pragma unroll
            for (int i = 0; i < 4; i++)
                #pragma unroll
                for (int jj = 0; jj < 4; jj++)
                    acc[i][jj] += xv[i].x*wv[jj].x + xv[i].y*wv[jj].y
                                + xv[i].z*wv[jj].z + xv[i].w*wv[jj].w;
        }
        __syncthreads();
    }
    float4 bv = make_float4(b_in[n0+tn*4+0], b_in[n0+tn*4+1],
                            b_in[n0+tn*4+2], b_in[n0+tn*4+3]);
    #pragma unroll
    for (int i = 0; i < 4; i++) {
        float4 o = make_float4(acc[i][0]+bv.x, acc[i][1]+bv.y,
                               acc[i][2]+bv.z, acc[i][3]+bv.w);
        *(float4*)&act[(size_t)(m0+tm*4+i)*HID + n0 + tn*4] = o;
    }
}

// ---------------------------------------------------------------------------
// Phase 2: sequential scan.
// 256 blocks = 32 groups (4 batch rows) x 8 slices (64 hidden j's).
// Each thread (j = t&63, q = t>>6) holds W_h[j0+j][q*128 .. q*128+127] in
// 128 VGPRs (loaded once). Per step: h (4x512) in LDS (broadcast reads),
// 512 FMA/thread, LDS partial reduction over the 4 k-quarters, epilogue,
// cross-block h exchange through LLC via agent-scope atomics + flag counter.
// ---------------------------------------------------------------------------
__global__ __launch_bounds__(256, 1) void scan_kernel(
    const float* __restrict__ noise, const float* __restrict__ W_h,
    const float* __restrict__ b_h, float* __restrict__ act,
    float* h_buf, int* flags)
{
    __shared__ __align__(16) float h_lds[4*512];   // 4 rows x 512
    __shared__ __align__(16) float part[4*64*4];   // [q][j][r]
    const int bid = blockIdx.x;
    const int g  = bid & (NGROUP-1);      // group: rows b0..b0+3 (same XCD set)
    const int p  = bid >> 5;              // slice: j0..j0+63
    const int b0 = g << 2;
    const int j0 = p << 6;
    const int t  = threadIdx.x;
    const int j  = t & 63;
    const int q  = t >> 6;                // k-quarter, also epilogue row r
    const int r  = q;

    // one-time: W_h slice row (j0+j), quarter q -> 128 VGPRs
    float wreg[128];
    {
        const float* wp = &W_h[(size_t)(j0+j)*HID + q*128];
        #pragma unroll
        for (int n = 0; n < 32; n++) {
            float4 v = *(const float4*)&wp[n*4];
            wreg[4*n+0] = v.x; wreg[4*n+1] = v.y;
            wreg[4*n+2] = v.z; wreg[4*n+3] = v.w;
        }
    }
    const float bh = b_h[j0 + j];

    for (int s = 0; s < SEQ; s++) {
        // prefetch this step's proj (in act region) and noise early
        const size_t eidx = ((size_t)(s*BATCH) + b0 + r)*HID + j0 + j;
        const float projv  = act[eidx];
        const float noisev = noise[eidx];

        if (s > 0 && t == 0) {
            while (__hip_atomic_load(&flags[(s-1)*NGROUP + g],
                                     __ATOMIC_RELAXED,
                                     __HIP_MEMORY_SCOPE_AGENT) < NSLICE) {}
        }
        __syncthreads();

        if (s == 0) {
            #pragma unroll
            for (int n = 0; n < 8; n++) h_lds[n*256 + t] = 0.f;
        } else {
            float* hb = &h_buf[((s-1)&1)*(BATCH*HID) + (size_t)b0*HID];
            #pragma unroll
            for (int n = 0; n < 8; n++) {
                int idx = n*256 + t;
                h_lds[idx] = __hip_atomic_load(&hb[idx], __ATOMIC_RELAXED,
                                               __HIP_MEMORY_SCOPE_AGENT);
            }
        }
        __syncthreads();

        // partial dot: acc[row] over k in [q*128, q*128+128)
        float a0 = 0.f, a1 = 0.f, a2 = 0.f, a3 = 0.f;
        const float* hq = &h_lds[q*128];
        #pragma unroll
        for (int kk = 0; kk < 128; kk += 4) {
            const float w0 = wreg[kk+0], w1 = wreg[kk+1];
            const float w2 = wreg[kk+2], w3 = wreg[kk+3];
            float4 h0v = *(const float4*)&hq[kk];
            float4 h1v = *(const float4*)&hq[kk + 512];
            float4 h2v = *(const float4*)&hq[kk + 1024];
            float4 h3v = *(const float4*)&hq[kk + 1536];
            a0 += w0*h0v.x + w1*h0v.y + w2*h0v.z + w3*h0v.w;
            a1 += w0*h1v.x + w1*h1v.y + w2*h1v.z + w3*h1v.w;
            a2 += w0*h2v.x + w1*h2v.y + w2*h2v.z + w3*h2v.w;
            a3 += w0*h3v.x + w1*h3v.y + w2*h3v.z + w3*h3v.w;
        }
        *(float4*)&part[(q*64 + j)*4] = make_float4(a0, a1, a2, a3);
        __syncthreads();

        // reduce the 4 k-quarter partials for output (row r, col j0+j)
        float pre = part[(0*64 + j)*4 + r] + part[(1*64 + j)*4 + r]
                  + part[(2*64 + j)*4 + r] + part[(3*64 + j)*4 + r];
        pre += projv + bh + SIGMA_F * noisev;
        const float hprev = h_lds[r*512 + j0 + j];
        const float hn = OMA_F*hprev + AL_F*fmaxf(pre, 0.f);

        act[eidx] = hn;  // overwrite proj slot with activity (same element)
        __hip_atomic_store(&h_buf[(s&1)*(BATCH*HID) + (size_t)(b0+r)*HID + j0 + j],
                           hn, __ATOMIC_RELAXED, __HIP_MEMORY_SCOPE_AGENT);
        __syncthreads();  // barrier drains vmcnt: all coherent stores complete
        if (t == 0) {
            __hip_atomic_fetch_add(&flags[s*NGROUP + g], 1,
                                   __ATOMIC_RELAXED, __HIP_MEMORY_SCOPE_AGENT);
        }
    }
}

// ---------------------------------------------------------------------------
// Phase 3: out[m,o] = sum_h act[m,h]*W_out[o,h] + b_out[o]
// Tiled 64(m) x 64(o=all), K=512 in eight 64-chunks.
// ---------------------------------------------------------------------------
__global__ __launch_bounds__(256) void out_gemm_kernel(
    const float* __restrict__ act, const float* __restrict__ W_out,
    const float* __restrict__ b_out, float* __restrict__ out)
{
    __shared__ __align__(16) float xs[64*68];
    __shared__ __align__(16) float ws[64*70];
    const int m0 = blockIdx.x << 6;
    const int t  = threadIdx.x;
    const int tm = t >> 4, tn = t & 15;
    float acc[4][4] = {{0.f,0.f,0.f,0.f},{0.f,0.f,0.f,0.f},
                       {0.f,0.f,0.f,0.f},{0.f,0.f,0.f,0.f}};
    for (int kc = 0; kc < HID; kc += 64) {
        #pragma unroll
        for (int n = 0; n < 4; n++) {
            int f = n*256 + t;
            int row = f >> 4, c4 = (f & 15) << 2;
            *(float4*)&xs[row*68 + c4] =
                *(const float4*)&act[(size_t)(m0+row)*HID + kc + c4];
        }
        #pragma unroll
        for (int n = 0; n < 4; n++) {
            int f = n*256 + t;
            int row = f >> 4, c4 = (f & 15) << 2;
            float4 v = *(const float4*)&W_out[(size_t)row*HID + kc + c4];
            *(float2*)&ws[row*70 + c4]     = make_float2(v.x, v.y);
            *(float2*)&ws[row*70 + c4 + 2] = make_float2(v.z, v.w);
        }
        __syncthreads();
        #pragma unroll
        for (int k = 0; k < 64; k += 4) {
            float4 xv[4]; float4 wv[4];
            #pragma unroll
            for (int i = 0; i < 4; i++)
                xv[i] = *(const float4*)&xs[(tm*4+i)*68 + k];
            #pragma unroll
            for (int jj = 0; jj < 4; jj++) {
                float2 a = *(const float2*)&ws[(tn*4+jj)*70 + k];
                float2 b = *(const float2*)&ws[(tn*4+jj)*70 + k + 2];
                wv[jj] = make_float4(a.x, a.y, b.x, b.y);
            }
            #pragma unroll
            for (int i = 0; i < 4; i++)
                #pragma unroll
                for (int jj = 0; jj < 4; jj++)
                    acc[i][jj] += xv[i].x*wv[jj].x + xv[i].y*wv[jj].y
                                + xv[i].z*wv[jj].z + xv[i].w*wv[jj].w;
        }
        __syncthreads();
    }
    float4 bv = make_float4(b_out[tn*4+0], b_out[tn*4+1],
                            b_out[tn*4+2], b_out[tn*4+3]);
    #pragma unroll
    for (int i = 0; i < 4; i++) {
        float4 o = make_float4(acc[i][0]+bv.x, acc[i][1]+bv.y,
                               acc[i][2]+bv.z, acc[i][3]+bv.w);
        *(float4*)&out[(size_t)(m0+tm*4+i)*OUTP + tn*4] = o;
    }
}

// ---------------------------------------------------------------------------
extern "C" void kernel_launch(void* const* d_in, const int* in_sizes, int n_in,
                              void* d_out, int out_size, void* d_ws, size_t ws_size,
                              hipStream_t stream)
{
    const float* x     = (const float*)d_in[0];
    const float* noise = (const float*)d_in[1];
    const float* W_in  = (const float*)d_in[2];
    const float* b_in  = (const float*)d_in[3];
    const float* W_h   = (const float*)d_in[4];
    const float* b_h   = (const float*)d_in[5];
    const float* W_out = (const float*)d_in[6];
    const float* b_out = (const float*)d_in[7];

    float* out = (float*)d_out;
    float* act = out + (size_t)M1*OUTP;          // rnn_activity region

    int*   flags = (int*)d_ws;                               // 1024*32 ints
    float* h_buf = (float*)((char*)d_ws + SEQ*NGROUP*sizeof(int)); // 2*128*512 f32

    hipMemsetAsync(flags, 0, SEQ*NGROUP*sizeof(int), stream);

    proj_gemm_kernel<<<dim3((M1/64)*(HID/64)), dim3(256), 0, stream>>>(
        x, W_in, b_in, act);
    scan_kernel<<<dim3(NGROUP*NSLICE), dim3(256), 0, stream>>>(
        noise, W_h, b_h, act, h_buf, flags);
    out_gemm_kernel<<<dim3(M1/64), dim3(256), 0, stream>>>(
        act, W_out, b_out, out);
}